// Round 10
// baseline (377.741 us; speedup 1.0000x reference)
//
#include <hip/hip_runtime.h>
#include <hip/hip_bf16.h>
#include <stdint.h>

typedef __bf16 bf16_t;
typedef bf16_t bf16x8 __attribute__((ext_vector_type(8)));
typedef float f32x4 __attribute__((ext_vector_type(4)));

#define IN_F 4096
#define OUT_F 4096
#define M_ROWS 8192
#define RANK 16

// ---------------------------------------------------------------------------
// Kernel 1 (merged prep): blocks [0,8192) dequant+LoRA-fold W -> bf16;
// blocks [8192, 24576) cast x f32 -> bf16.
// ---------------------------------------------------------------------------
__global__ __launch_bounds__(256)
void prep_kernel(const float* __restrict__ x, const int* __restrict__ qw,
                 const float* __restrict__ wmax, const float* __restrict__ lA,
                 const float* __restrict__ lB, bf16_t* __restrict__ Wp,
                 bf16_t* __restrict__ Xb) {
  const int b = blockIdx.x;
  if (b >= 8192) {
    const size_t tid = (size_t)(b - 8192) * 256 + threadIdx.x;
    const float4 a0 = *(const float4*)(x + tid * 8);
    const float4 a1 = *(const float4*)(x + tid * 8 + 4);
    bf16x8 o;
    o[0] = (bf16_t)a0.x; o[1] = (bf16_t)a0.y; o[2] = (bf16_t)a0.z; o[3] = (bf16_t)a0.w;
    o[4] = (bf16_t)a1.x; o[5] = (bf16_t)a1.y; o[6] = (bf16_t)a1.z; o[7] = (bf16_t)a1.w;
    *(bf16x8*)(Xb + tid * 8) = o;
    return;
  }
  const int bo = b >> 4;
  const int bi = b & 15;
  const int t  = threadIdx.x;
  const int o  = bo * 8 + (t >> 5);
  const int i0 = bi * 256 + (t & 31) * 8;
  const int f0 = o * IN_F + i0;

  const int4 q4 = *(const int4*)(qw + (f0 >> 1));
  const float scale = wmax[f0 >> 6];
  const float st = scale * (2.0f / 15.0f);

  float v[8];
  {
    const int q0 = q4.x, q1 = q4.y, q2 = q4.z, q3 = q4.w;
    v[0] = (float)(q0 & 15)        * st - scale;
    v[1] = (float)((q0 >> 4) & 15) * st - scale;
    v[2] = (float)(q1 & 15)        * st - scale;
    v[3] = (float)((q1 >> 4) & 15) * st - scale;
    v[4] = (float)(q2 & 15)        * st - scale;
    v[5] = (float)((q2 >> 4) & 15) * st - scale;
    v[6] = (float)(q3 & 15)        * st - scale;
    v[7] = (float)((q3 >> 4) & 15) * st - scale;
  }

  const float* Brow = lB + o * RANK;
#pragma unroll
  for (int r = 0; r < RANK; ++r) {
    const float br = Brow[r];
    const float4 a0 = *(const float4*)(lA + r * IN_F + i0);
    const float4 a1 = *(const float4*)(lA + r * IN_F + i0 + 4);
    v[0] += br * a0.x; v[1] += br * a0.y; v[2] += br * a0.z; v[3] += br * a0.w;
    v[4] += br * a1.x; v[5] += br * a1.y; v[6] += br * a1.z; v[7] += br * a1.w;
  }

  bf16x8 ov;
#pragma unroll
  for (int j = 0; j < 8; ++j) ov[j] = (bf16_t)v[j];
  *(bf16x8*)(Wp + (size_t)f0) = ov;
}

// ---------------------------------------------------------------------------
// Kernel 2: 128x256 GEMM, BK=32, TRIPLE-buffered LDS (72 KiB), one
// vmcnt(3)+barrier per tile, and an UNFENCED interleaved body: ds_reads for
// tile t+1 woven between tile t's MFMAs, no sched_barrier/setprio anywhere —
// the compiler co-schedules LDS and matrix pipes (m196/m97 evidence).
// Register frags double-banked E/O (static names). 0-conflict slot swizzle.
// ---------------------------------------------------------------------------
__device__ __forceinline__ void gld(const bf16_t* src, char* dst) {
  __builtin_amdgcn_global_load_lds((const __attribute__((address_space(1))) void*)src,
                                   (__attribute__((address_space(3))) void*)dst, 16, 0, 0);
}

#define BARRIER() __builtin_amdgcn_s_barrier()
#define WAIT_VM(n) asm volatile("s_waitcnt vmcnt(" #n ")" ::: "memory")

// one K-tile stage: A 8 KB (1 gload, 128 rows) + B 16 KB (2 gloads, 256 rows)
#define STAGE(kt, buf) do { \
  gld(Asrc + (size_t)(kt) * 32,                      ldsA + (buf)*8192  + tid*16); \
  gld(Bsrc + (size_t)(kt) * 32,                      ldsB + (buf)*16384 + tid*16); \
  gld(Bsrc + (size_t)128*IN_F + (size_t)(kt) * 32,   ldsB + (buf)*16384 + 8192 + tid*16); \
} while (0)

#define LDAf(buf, m) (*(const bf16x8*)(ldsA + (buf)*8192  + aRowB + (m)*1024 + cSw))
#define LDBf(buf, n) (*(const bf16x8*)(ldsB + (buf)*16384 + bRowB + (n)*1024 + cSw))

#define MFMA4(m, AB, BB) do { \
  _Pragma("unroll") for (int n = 0; n < 4; ++n) \
    acc[m][n] = __builtin_amdgcn_mfma_f32_16x16x32_bf16(AB[m], BB[n], acc[m][n], 0, 0, 0); \
} while (0)

// Tile t: MFMA from bank M (loaded last tile), reads(t+1) from buf R into
// bank W, stage(t+3) into buf S. STG empty in tail. Interleaved, unfenced.
#define TILE(R, S, WA, WB, MA, MB, STG, VMW) do { \
  VMW; BARRIER(); \
  STG; \
  WA[0] = LDAf(R, 0); WB[0] = LDBf(R, 0); \
  MFMA4(0, MA, MB); \
  WA[1] = LDAf(R, 1); WB[1] = LDBf(R, 1); \
  MFMA4(1, MA, MB); \
  WA[2] = LDAf(R, 2); WB[2] = LDBf(R, 2); \
  MFMA4(2, MA, MB); \
  WA[3] = LDAf(R, 3); WB[3] = LDBf(R, 3); \
  MFMA4(3, MA, MB); \
} while (0)

__global__ __launch_bounds__(512)
void gemm_ilv_kernel(const bf16_t* __restrict__ Xb, const bf16_t* __restrict__ Wp,
                     const float* __restrict__ bias, float* __restrict__ C) {
  __shared__ __align__(16) bf16_t As[3 * 4096];    // 24 KiB: [3buf][128 rows][64 B]
  __shared__ __align__(16) bf16_t Bs[3 * 8192];    // 48 KiB: [3buf][256 rows][64 B]
  char* ldsA = (char*)As;
  char* ldsB = (char*)Bs;

  const int tid  = threadIdx.x;
  const int lane = tid & 63;
  const int wave = tid >> 6;
  const int wr = wave >> 2;            // 0..1 -> M half (64 rows)
  const int wc = wave & 3;             // 0..3 -> N quarter (64 cols)
  const int r16 = lane & 15;
  const int kg  = lane >> 4;           // 0..3

  // bijective XCD swizzle: 1024 wgs, 128/XCD chunk
  const int bid  = blockIdx.x;
  const int wgid = (bid & 7) * 128 + (bid >> 3);
  const int bm = wgid >> 4;            // 0..63
  const int bn = wgid & 15;            // 0..15

  // staging: linear dest tid*16; source slot = (tid&3) ^ ((tid>>3)&3)
  const int srow = tid >> 2;                        // 0..127
  const int ss   = (tid & 3) ^ ((tid >> 3) & 3);
  const bf16_t* Asrc = Xb + (size_t)(bm * 128 + srow) * IN_F + ss * 8;
  const bf16_t* Bsrc = Wp + (size_t)(bn * 256 + srow) * IN_F + ss * 8;

  // read side: row*64 bytes; slot byte = (kg ^ ((r16>>1)&3))*16  (0-conflict)
  const int cSw   = (kg ^ ((r16 >> 1) & 3)) * 16;
  const int aRowB = (wr * 64 + r16) * 64;           // + m*1024
  const int bRowB = (wc * 64 + r16) * 64;           // + n*1024

  f32x4 acc[4][4] = {};
  bf16x8 eA[4], eB[4], oA[4], oB[4];

  // prologue: stage tiles 0,1,2; preload bank E with tile-0 fragments
  STAGE(0, 0); STAGE(1, 1); STAGE(2, 2);
  WAIT_VM(6);                   // tile 0 landed; tiles 1,2 in flight
  BARRIER();
#pragma unroll
  for (int m = 0; m < 4; ++m) { eA[m] = LDAf(0, m); eB[m] = LDBf(0, m); }

  // main: t = 0..119, 6 tiles/iter (buf%3, bank%2 both static)
  for (int tt = 0; tt < 120; tt += 6) {
    TILE(1, 0, oA, oB, eA, eB, STAGE(tt + 3, 0), WAIT_VM(3));   // t=tt+0 (E)
    TILE(2, 1, eA, eB, oA, oB, STAGE(tt + 4, 1), WAIT_VM(3));   // t=tt+1 (O)
    TILE(0, 2, oA, oB, eA, eB, STAGE(tt + 5, 2), WAIT_VM(3));   // t=tt+2 (E)
    TILE(1, 0, eA, eB, oA, oB, STAGE(tt + 6, 0), WAIT_VM(3));   // t=tt+3 (O)
    TILE(2, 1, oA, oB, eA, eB, STAGE(tt + 7, 1), WAIT_VM(3));   // t=tt+4 (E)
    TILE(0, 2, eA, eB, oA, oB, STAGE(tt + 8, 2), WAIT_VM(3));   // t=tt+5 (O)
  }
  // tail: t=120..127 (tiles 123..127 staged at t=120..124)
  TILE(1, 0, oA, oB, eA, eB, STAGE(123, 0), WAIT_VM(3));        // t=120 (E)
  TILE(2, 1, eA, eB, oA, oB, STAGE(124, 1), WAIT_VM(3));        // t=121 (O)
  TILE(0, 2, oA, oB, eA, eB, STAGE(125, 2), WAIT_VM(3));        // t=122 (E)
  TILE(1, 0, eA, eB, oA, oB, STAGE(126, 0), WAIT_VM(3));        // t=123 (O)
  TILE(2, 1, oA, oB, eA, eB, STAGE(127, 1), WAIT_VM(3));        // t=124 (E)
  TILE(0, 2, eA, eB, oA, oB, {},            WAIT_VM(3));        // t=125 (O)
  TILE(1, 2, oA, oB, eA, eB, {},            WAIT_VM(0));        // t=126 (E) reads 127
  { BARRIER();                                                   // t=127 (O)
    MFMA4(0, oA, oB); MFMA4(1, oA, oB); MFMA4(2, oA, oB); MFMA4(3, oA, oB); }

  // epilogue: C/D layout col=lane&15, row=kg*4+reg (m89-verified)
#pragma unroll
  for (int n = 0; n < 4; ++n) {
    const int col = bn * 256 + wc * 64 + n * 16 + r16;
    const float bv = bias[col];
#pragma unroll
    for (int m = 0; m < 4; ++m) {
      const int row0 = bm * 128 + wr * 64 + m * 16 + kg * 4;
#pragma unroll
      for (int r = 0; r < 4; ++r)
        C[(size_t)(row0 + r) * OUT_F + col] = acc[m][n][r] + bv;
    }
  }
}

// ---------------------------------------------------------------------------
extern "C" void kernel_launch(void* const* d_in, const int* in_sizes, int n_in,
                              void* d_out, int out_size, void* d_ws, size_t ws_size,
                              hipStream_t stream) {
  const float* x  = (const float*)d_in[0];
  const int*   qw = (const int*)d_in[1];
  const float* wm = (const float*)d_in[2];
  const float* lA = (const float*)d_in[3];
  const float* lB = (const float*)d_in[4];
  const float* bs = (const float*)d_in[5];
  float* out = (float*)d_out;

  bf16_t* Wp = (bf16_t*)d_ws;                                        // 33.5 MB
  bf16_t* Xb = (bf16_t*)((char*)d_ws + (size_t)OUT_F * IN_F * 2);    // 67 MB

  prep_kernel<<<24576, 256, 0, stream>>>(x, qw, wm, lA, lB, Wp, Xb);
  gemm_ilv_kernel<<<(M_ROWS / 128) * (OUT_F / 256), 512, 0, stream>>>(Xb, Wp, bs, out);
}

// Round 11
// 338.295 us; speedup vs baseline: 1.1166x; 1.1166x over previous
//
#include <hip/hip_runtime.h>
#include <hip/hip_bf16.h>
#include <stdint.h>

typedef __bf16 bf16_t;
typedef bf16_t bf16x8 __attribute__((ext_vector_type(8)));
typedef float f32x4 __attribute__((ext_vector_type(4)));
typedef float f32x16 __attribute__((ext_vector_type(16)));

#define IN_F 4096
#define OUT_F 4096
#define M_ROWS 8192
#define RANK 16

// ---------------------------------------------------------------------------
// Kernel 1 (merged prep): blocks [0,8192) dequant+LoRA-fold W -> bf16;
// blocks [8192, 24576) cast x f32 -> bf16.
// ---------------------------------------------------------------------------
__global__ __launch_bounds__(256)
void prep_kernel(const float* __restrict__ x, const int* __restrict__ qw,
                 const float* __restrict__ wmax, const float* __restrict__ lA,
                 const float* __restrict__ lB, bf16_t* __restrict__ Wp,
                 bf16_t* __restrict__ Xb) {
  const int b = blockIdx.x;
  if (b >= 8192) {
    const size_t tid = (size_t)(b - 8192) * 256 + threadIdx.x;
    const float4 a0 = *(const float4*)(x + tid * 8);
    const float4 a1 = *(const float4*)(x + tid * 8 + 4);
    bf16x8 o;
    o[0] = (bf16_t)a0.x; o[1] = (bf16_t)a0.y; o[2] = (bf16_t)a0.z; o[3] = (bf16_t)a0.w;
    o[4] = (bf16_t)a1.x; o[5] = (bf16_t)a1.y; o[6] = (bf16_t)a1.z; o[7] = (bf16_t)a1.w;
    *(bf16x8*)(Xb + tid * 8) = o;
    return;
  }
  const int bo = b >> 4;
  const int bi = b & 15;
  const int t  = threadIdx.x;
  const int o  = bo * 8 + (t >> 5);
  const int i0 = bi * 256 + (t & 31) * 8;
  const int f0 = o * IN_F + i0;

  const int4 q4 = *(const int4*)(qw + (f0 >> 1));
  const float scale = wmax[f0 >> 6];
  const float st = scale * (2.0f / 15.0f);

  float v[8];
  {
    const int q0 = q4.x, q1 = q4.y, q2 = q4.z, q3 = q4.w;
    v[0] = (float)(q0 & 15)        * st - scale;
    v[1] = (float)((q0 >> 4) & 15) * st - scale;
    v[2] = (float)(q1 & 15)        * st - scale;
    v[3] = (float)((q1 >> 4) & 15) * st - scale;
    v[4] = (float)(q2 & 15)        * st - scale;
    v[5] = (float)((q2 >> 4) & 15) * st - scale;
    v[6] = (float)(q3 & 15)        * st - scale;
    v[7] = (float)((q3 >> 4) & 15) * st - scale;
  }

  const float* Brow = lB + o * RANK;
#pragma unroll
  for (int r = 0; r < RANK; ++r) {
    const float br = Brow[r];
    const float4 a0 = *(const float4*)(lA + r * IN_F + i0);
    const float4 a1 = *(const float4*)(lA + r * IN_F + i0 + 4);
    v[0] += br * a0.x; v[1] += br * a0.y; v[2] += br * a0.z; v[3] += br * a0.w;
    v[4] += br * a1.x; v[5] += br * a1.y; v[6] += br * a1.z; v[7] += br * a1.w;
  }

  bf16x8 ov;
#pragma unroll
  for (int j = 0; j < 8; ++j) ov[j] = (bf16_t)v[j];
  *(bf16x8*)(Wp + (size_t)f0) = ov;
}

// ---------------------------------------------------------------------------
// Kernel 2: 256x256 8-phase GEMM (r2 structure verbatim) with the
// 32x32x16 MFMA shape (2495 TF shape-ceiling vs 2075 for 16x16; half the
// MFMA instruction count). Wave tile 128x64 = 4m x 2n of 32x32;
// phase P computes m-tile P (4 k-chunks x 2 n = 8 MFMAs).
// A/B operand: lane row = lane&31, k-slot = (lane>>5)*8.
// D: col = lane&31, row = 4*(lane>>5) + (reg&3) + 8*(reg>>2)   [m74/m101]
// Swizzle: col_byte = (c*32 | kg2*16) ^ ((lane&7)*16); every 8-lane group
// covers all 32 banks. Staging: linear dest + inverse-XOR source (rule #21).
// ---------------------------------------------------------------------------
__device__ __forceinline__ void gld(const bf16_t* src, char* dst) {
  __builtin_amdgcn_global_load_lds((const __attribute__((address_space(1))) void*)src,
                                   (__attribute__((address_space(3))) void*)dst, 16, 0, 0);
}

#define BARRIER() __builtin_amdgcn_s_barrier()
#define WAIT_LGKM0() do { asm volatile("s_waitcnt lgkmcnt(0)" ::: "memory"); \
                          __builtin_amdgcn_sched_barrier(0); } while (0)
#define WAIT_VM(n) asm volatile("s_waitcnt vmcnt(" #n ")" ::: "memory")

#define STAGE_A(kt, buf) do { \
  _Pragma("unroll") for (int g = 0; g < 4; ++g) \
    gld(Asrc + ((size_t)g*64*IN_F + (size_t)(kt)*64), ldsA + ((buf)*32768 + g*8192 + tid*16)); \
} while (0)
#define STAGE_B_HALF(kt, buf, h) do { \
  _Pragma("unroll") for (int g = 0; g < 2; ++g) \
    gld(Bsrc + ((size_t)((h)*2+g)*64*IN_F + (size_t)(kt)*64), \
        ldsB + ((buf)*32768 + ((h)*2+g)*8192 + tid*16)); \
} while (0)
#define STAGE_B(kt, buf) do { STAGE_B_HALF(kt, buf, 0); STAGE_B_HALF(kt, buf, 1); } while (0)

// fragment reads: cc[c] is the swizzled k-chunk column byte
#define LDA32(buf, P, c) (*(const bf16x8*)(ldsA + ((buf)*32768 + aBase + (P)*4096 + cc##c)))
#define LDB32(buf, nt, c) (*(const bf16x8*)(ldsB + ((buf)*32768 + bBase + (nt)*4096 + cc##c)))

#define READ_B_ALL(buf) do { \
  bT[0][0] = LDB32(buf, 0, 0); bT[0][1] = LDB32(buf, 0, 1); \
  bT[0][2] = LDB32(buf, 0, 2); bT[0][3] = LDB32(buf, 0, 3); \
  bT[1][0] = LDB32(buf, 1, 0); bT[1][1] = LDB32(buf, 1, 1); \
  bT[1][2] = LDB32(buf, 1, 2); bT[1][3] = LDB32(buf, 1, 3); \
} while (0)

#define PHASE(P, EXTRA, STAGE, TAILWAIT) do { \
  aF[0] = LDA32(cur, P, 0); aF[1] = LDA32(cur, P, 1); \
  aF[2] = LDA32(cur, P, 2); aF[3] = LDA32(cur, P, 3); \
  EXTRA; STAGE; \
  BARRIER(); \
  WAIT_LGKM0(); \
  __builtin_amdgcn_s_setprio(1); \
  _Pragma("unroll") for (int c = 0; c < 4; ++c) \
    _Pragma("unroll") for (int nt = 0; nt < 2; ++nt) \
      acc[P][nt] = __builtin_amdgcn_mfma_f32_32x32x16_bf16( \
          aF[c], bT[nt][c], acc[P][nt], 0, 0, 0); \
  __builtin_amdgcn_s_setprio(0); \
  TAILWAIT; \
  BARRIER(); \
} while (0)

__global__ __launch_bounds__(512, 2)
void gemm_32x32_kernel(const bf16_t* __restrict__ Xb, const bf16_t* __restrict__ Wp,
                       const float* __restrict__ bias, float* __restrict__ C) {
  __shared__ __align__(16) bf16_t As[2 * 16384];   // [2buf][256 rows][64 cols]
  __shared__ __align__(16) bf16_t Bs[2 * 16384];
  char* ldsA = (char*)As;
  char* ldsB = (char*)Bs;

  const int tid  = threadIdx.x;
  const int lane = tid & 63;
  const int wave = tid >> 6;
  const int wr = wave >> 2;           // 0..1 -> M half (128 rows)
  const int wc = wave & 3;            // 0..3 -> N quarter (64 cols)
  const int l31 = lane & 31;          // operand row
  const int kg2 = lane >> 5;          // k-slot (8 bf16)

  // bijective XCD swizzle (nwg=512, 512%8==0)
  const int bid  = blockIdx.x;
  const int wgid = (bid & 7) * 64 + (bid >> 3);
  const int bm = wgid >> 4;           // 0..31
  const int bn = wgid & 15;           // 0..15

  // staging: linear dest tid*16; source col inverse-XOR'd (rule #21)
  const int srow = tid >> 3;                          // 0..63 (+g*64)
  const int scol = ((tid & 7) ^ (srow & 7)) * 8;      // element col
  const bf16_t* Asrc = Xb + (size_t)(bm * 256 + srow) * IN_F + scol;
  const bf16_t* Bsrc = Wp + (size_t)(bn * 256 + srow) * IN_F + scol;

  // read-side bases (row*128 bytes) and swizzled k-chunk cols
  const int aBase = wr * 16384 + l31 * 128;           // + P*4096 + cc
  const int bBase = wc * 8192  + l31 * 128;           // + nt*4096 + cc
  const int xr  = (lane & 7) * 16;
  const int cc0 = (0  | kg2 * 16) ^ xr;
  const int cc1 = (32 | kg2 * 16) ^ xr;
  const int cc2 = (64 | kg2 * 16) ^ xr;
  const int cc3 = (96 | kg2 * 16) ^ xr;

  f32x16 acc[4][2] = {};
  bf16x8 aF[4], bT[2][4];

  // prologue: stage K-tiles 0 and 1
  STAGE_A(0, 0); STAGE_B(0, 0);
  STAGE_A(1, 1); STAGE_B(1, 1);
  WAIT_VM(8);            // tile 0 landed; tile 1's 8 loads in flight
  BARRIER();

  for (int t = 0; t < 64; ++t) {
    const int cur = t & 1;
    PHASE(0, READ_B_ALL(cur),
          { if (t >= 1 && t < 63) STAGE_A(t + 1, cur ^ 1); }, {});
    PHASE(1, {},
          { if (t < 62) STAGE_B_HALF(t + 2, cur, 0); }, {});
    PHASE(2, {},
          { if (t < 62) STAGE_B_HALF(t + 2, cur, 1); }, {});
    PHASE(3, {}, {},
          { if (t < 62) { WAIT_VM(4); } else if (t == 62) { WAIT_VM(0); } });
  }

  // epilogue: D col=lane&31, row = 4*kg2 + (reg&3) + 8*(reg>>2)  [m74/m101]
#pragma unroll
  for (int nt = 0; nt < 2; ++nt) {
    const int col = bn * 256 + wc * 64 + nt * 32 + l31;
    const float bv = bias[col];
#pragma unroll
    for (int mt = 0; mt < 4; ++mt) {
      const int rowbase = bm * 256 + wr * 128 + mt * 32 + kg2 * 4;
#pragma unroll
      for (int reg = 0; reg < 16; ++reg) {
        const int row = rowbase + (reg & 3) + 8 * (reg >> 2);
        C[(size_t)row * OUT_F + col] = acc[mt][nt][reg] + bv;
      }
    }
  }
}

// ---------------------------------------------------------------------------
extern "C" void kernel_launch(void* const* d_in, const int* in_sizes, int n_in,
                              void* d_out, int out_size, void* d_ws, size_t ws_size,
                              hipStream_t stream) {
  const float* x  = (const float*)d_in[0];
  const int*   qw = (const int*)d_in[1];
  const float* wm = (const float*)d_in[2];
  const float* lA = (const float*)d_in[3];
  const float* lB = (const float*)d_in[4];
  const float* bs = (const float*)d_in[5];
  float* out = (float*)d_out;

  bf16_t* Wp = (bf16_t*)d_ws;                                        // 33.5 MB
  bf16_t* Xb = (bf16_t*)((char*)d_ws + (size_t)OUT_F * IN_F * 2);    // 67 MB

  prep_kernel<<<24576, 256, 0, stream>>>(x, qw, wm, lA, lB, Wp, Xb);
  gemm_32x32_kernel<<<(M_ROWS / 256) * (OUT_F / 256), 512, 0, stream>>>(Xb, Wp, bs, out);
}

// Round 12
// 337.648 us; speedup vs baseline: 1.1187x; 1.0019x over previous
//
#include <hip/hip_runtime.h>
#include <hip/hip_bf16.h>
#include <stdint.h>

typedef __bf16 bf16_t;
typedef bf16_t bf16x8 __attribute__((ext_vector_type(8)));
typedef float f32x4 __attribute__((ext_vector_type(4)));
typedef float f32x16 __attribute__((ext_vector_type(16)));

#define IN_F 4096
#define OUT_F 4096
#define M_ROWS 8192
#define RANK 16

// ---------------------------------------------------------------------------
// Kernel 1 (merged prep): blocks [0,8192) dequant+LoRA-fold W -> bf16;
// blocks [8192, 24576) cast x f32 -> bf16.
// ---------------------------------------------------------------------------
__global__ __launch_bounds__(256)
void prep_kernel(const float* __restrict__ x, const int* __restrict__ qw,
                 const float* __restrict__ wmax, const float* __restrict__ lA,
                 const float* __restrict__ lB, bf16_t* __restrict__ Wp,
                 bf16_t* __restrict__ Xb) {
  const int b = blockIdx.x;
  if (b >= 8192) {
    const size_t tid = (size_t)(b - 8192) * 256 + threadIdx.x;
    const float4 a0 = *(const float4*)(x + tid * 8);
    const float4 a1 = *(const float4*)(x + tid * 8 + 4);
    bf16x8 o;
    o[0] = (bf16_t)a0.x; o[1] = (bf16_t)a0.y; o[2] = (bf16_t)a0.z; o[3] = (bf16_t)a0.w;
    o[4] = (bf16_t)a1.x; o[5] = (bf16_t)a1.y; o[6] = (bf16_t)a1.z; o[7] = (bf16_t)a1.w;
    *(bf16x8*)(Xb + tid * 8) = o;
    return;
  }
  const int bo = b >> 4;
  const int bi = b & 15;
  const int t  = threadIdx.x;
  const int o  = bo * 8 + (t >> 5);
  const int i0 = bi * 256 + (t & 31) * 8;
  const int f0 = o * IN_F + i0;

  const int4 q4 = *(const int4*)(qw + (f0 >> 1));
  const float scale = wmax[f0 >> 6];
  const float st = scale * (2.0f / 15.0f);

  float v[8];
  {
    const int q0 = q4.x, q1 = q4.y, q2 = q4.z, q3 = q4.w;
    v[0] = (float)(q0 & 15)        * st - scale;
    v[1] = (float)((q0 >> 4) & 15) * st - scale;
    v[2] = (float)(q1 & 15)        * st - scale;
    v[3] = (float)((q1 >> 4) & 15) * st - scale;
    v[4] = (float)(q2 & 15)        * st - scale;
    v[5] = (float)((q2 >> 4) & 15) * st - scale;
    v[6] = (float)(q3 & 15)        * st - scale;
    v[7] = (float)((q3 >> 4) & 15) * st - scale;
  }

  const float* Brow = lB + o * RANK;
#pragma unroll
  for (int r = 0; r < RANK; ++r) {
    const float br = Brow[r];
    const float4 a0 = *(const float4*)(lA + r * IN_F + i0);
    const float4 a1 = *(const float4*)(lA + r * IN_F + i0 + 4);
    v[0] += br * a0.x; v[1] += br * a0.y; v[2] += br * a0.z; v[3] += br * a0.w;
    v[4] += br * a1.x; v[5] += br * a1.y; v[6] += br * a1.z; v[7] += br * a1.w;
  }

  bf16x8 ov;
#pragma unroll
  for (int j = 0; j < 8; ++j) ov[j] = (bf16_t)v[j];
  *(bf16x8*)(Wp + (size_t)f0) = ov;
}

// ---------------------------------------------------------------------------
// Kernel 2: 256x256 8-phase GEMM, 32x32x16 MFMA, FIXED swizzle.
// Conflict model (from r2/r5/r9=0 vs r8/r11=2.5e7): LDS co-issues lanes
// i and i+16 on b128 reads -> their slots must differ.
// slot(q,row) = q ^ (row&7) ^ ((row>>2)&4), q = c*2+kg2:
//   bit0 separates i/i+32 (kg2), bit2 separates i/i+16 (row bit4),
//   bits0-2 separate each 8-lane group. XOR-const per row -> bijective.
// Staging: linear gload dest + same involution on source col (rule #21).
// Row bits used (&7, &16) invariant under wr/P/nt/wc offsets (all mult. 32).
// ---------------------------------------------------------------------------
__device__ __forceinline__ void gld(const bf16_t* src, char* dst) {
  __builtin_amdgcn_global_load_lds((const __attribute__((address_space(1))) void*)src,
                                   (__attribute__((address_space(3))) void*)dst, 16, 0, 0);
}

#define BARRIER() __builtin_amdgcn_s_barrier()
#define WAIT_LGKM0() do { asm volatile("s_waitcnt lgkmcnt(0)" ::: "memory"); \
                          __builtin_amdgcn_sched_barrier(0); } while (0)
#define WAIT_VM(n) asm volatile("s_waitcnt vmcnt(" #n ")" ::: "memory")

#define STAGE_A(kt, buf) do { \
  _Pragma("unroll") for (int g = 0; g < 4; ++g) \
    gld(Asrc + ((size_t)g*64*IN_F + (size_t)(kt)*64), ldsA + ((buf)*32768 + g*8192 + tid*16)); \
} while (0)
#define STAGE_B_HALF(kt, buf, h) do { \
  _Pragma("unroll") for (int g = 0; g < 2; ++g) \
    gld(Bsrc + ((size_t)((h)*2+g)*64*IN_F + (size_t)(kt)*64), \
        ldsB + ((buf)*32768 + ((h)*2+g)*8192 + tid*16)); \
} while (0)
#define STAGE_B(kt, buf) do { STAGE_B_HALF(kt, buf, 0); STAGE_B_HALF(kt, buf, 1); } while (0)

// fragment reads: cc[c] is the swizzled k-chunk column byte
#define LDA32(buf, P, c) (*(const bf16x8*)(ldsA + ((buf)*32768 + aBase + (P)*4096 + cc##c)))
#define LDB32(buf, nt, c) (*(const bf16x8*)(ldsB + ((buf)*32768 + bBase + (nt)*4096 + cc##c)))

#define READ_B_ALL(buf) do { \
  bT[0][0] = LDB32(buf, 0, 0); bT[0][1] = LDB32(buf, 0, 1); \
  bT[0][2] = LDB32(buf, 0, 2); bT[0][3] = LDB32(buf, 0, 3); \
  bT[1][0] = LDB32(buf, 1, 0); bT[1][1] = LDB32(buf, 1, 1); \
  bT[1][2] = LDB32(buf, 1, 2); bT[1][3] = LDB32(buf, 1, 3); \
} while (0)

#define PHASE(P, EXTRA, STAGE, TAILWAIT) do { \
  aF[0] = LDA32(cur, P, 0); aF[1] = LDA32(cur, P, 1); \
  aF[2] = LDA32(cur, P, 2); aF[3] = LDA32(cur, P, 3); \
  EXTRA; STAGE; \
  BARRIER(); \
  WAIT_LGKM0(); \
  __builtin_amdgcn_s_setprio(1); \
  _Pragma("unroll") for (int c = 0; c < 4; ++c) \
    _Pragma("unroll") for (int nt = 0; nt < 2; ++nt) \
      acc[P][nt] = __builtin_amdgcn_mfma_f32_32x32x16_bf16( \
          aF[c], bT[nt][c], acc[P][nt], 0, 0, 0); \
  __builtin_amdgcn_s_setprio(0); \
  TAILWAIT; \
  BARRIER(); \
} while (0)

__global__ __launch_bounds__(512, 2)
void gemm_32x32f_kernel(const bf16_t* __restrict__ Xb, const bf16_t* __restrict__ Wp,
                        const float* __restrict__ bias, float* __restrict__ C) {
  __shared__ __align__(16) bf16_t As[2 * 16384];   // [2buf][256 rows][64 cols]
  __shared__ __align__(16) bf16_t Bs[2 * 16384];
  char* ldsA = (char*)As;
  char* ldsB = (char*)Bs;

  const int tid  = threadIdx.x;
  const int lane = tid & 63;
  const int wave = tid >> 6;
  const int wr = wave >> 2;           // 0..1 -> M half (128 rows)
  const int wc = wave & 3;            // 0..3 -> N quarter (64 cols)
  const int l31 = lane & 31;          // operand row
  const int kg2 = lane >> 5;          // k-slot (8 bf16)

  // bijective XCD swizzle (nwg=512, 512%8==0)
  const int bid  = blockIdx.x;
  const int wgid = (bid & 7) * 64 + (bid >> 3);
  const int bm = wgid >> 4;           // 0..31
  const int bn = wgid & 15;           // 0..15

  // staging: linear dest tid*16; source chunk-slot = involution of dest slot
  const int srow = tid >> 3;                                        // 0..63 (+g*64)
  const int ss   = (tid & 7) ^ (srow & 7) ^ ((tid >> 5) & 4);       // chunk-slot
  const bf16_t* Asrc = Xb + (size_t)(bm * 256 + srow) * IN_F + ss * 8;
  const bf16_t* Bsrc = Wp + (size_t)(bn * 256 + srow) * IN_F + ss * 8;

  // read-side bases (row*128 bytes) and swizzled k-chunk column bytes
  const int aBase = wr * 16384 + l31 * 128;           // + P*4096 + cc
  const int bBase = wc * 8192  + l31 * 128;           // + nt*4096 + cc
  const int xr  = ((l31 & 7) ^ ((l31 >> 2) & 4)) * 16;
  const int cc0 = (0  + kg2 * 16) ^ xr;
  const int cc1 = (32 + kg2 * 16) ^ xr;
  const int cc2 = (64 + kg2 * 16) ^ xr;
  const int cc3 = (96 + kg2 * 16) ^ xr;

  f32x16 acc[4][2] = {};
  bf16x8 aF[4], bT[2][4];

  // prologue: stage K-tiles 0 and 1
  STAGE_A(0, 0); STAGE_B(0, 0);
  STAGE_A(1, 1); STAGE_B(1, 1);
  WAIT_VM(8);            // tile 0 landed; tile 1's 8 loads in flight
  BARRIER();

  for (int t = 0; t < 64; ++t) {
    const int cur = t & 1;
    PHASE(0, READ_B_ALL(cur),
          { if (t >= 1 && t < 63) STAGE_A(t + 1, cur ^ 1); }, {});
    PHASE(1, {},
          { if (t < 62) STAGE_B_HALF(t + 2, cur, 0); }, {});
    PHASE(2, {},
          { if (t < 62) STAGE_B_HALF(t + 2, cur, 1); }, {});
    PHASE(3, {}, {},
          { if (t < 62) { WAIT_VM(4); } else if (t == 62) { WAIT_VM(0); } });
  }

  // epilogue: D col=lane&31, row = 4*kg2 + (reg&3) + 8*(reg>>2)  [m74/m101]
#pragma unroll
  for (int nt = 0; nt < 2; ++nt) {
    const int col = bn * 256 + wc * 64 + nt * 32 + l31;
    const float bv = bias[col];
#pragma unroll
    for (int mt = 0; mt < 4; ++mt) {
      const int rowbase = bm * 256 + wr * 128 + mt * 32 + kg2 * 4;
#pragma unroll
      for (int reg = 0; reg < 16; ++reg) {
        const int row = rowbase + (reg & 3) + 8 * (reg >> 2);
        C[(size_t)row * OUT_F + col] = acc[mt][nt][reg] + bv;
      }
    }
  }
}

// ---------------------------------------------------------------------------
extern "C" void kernel_launch(void* const* d_in, const int* in_sizes, int n_in,
                              void* d_out, int out_size, void* d_ws, size_t ws_size,
                              hipStream_t stream) {
  const float* x  = (const float*)d_in[0];
  const int*   qw = (const int*)d_in[1];
  const float* wm = (const float*)d_in[2];
  const float* lA = (const float*)d_in[3];
  const float* lB = (const float*)d_in[4];
  const float* bs = (const float*)d_in[5];
  float* out = (float*)d_out;

  bf16_t* Wp = (bf16_t*)d_ws;                                        // 33.5 MB
  bf16_t* Xb = (bf16_t*)((char*)d_ws + (size_t)OUT_F * IN_F * 2);    // 67 MB

  prep_kernel<<<24576, 256, 0, stream>>>(x, qw, wm, lA, lB, Wp, Xb);
  gemm_32x32f_kernel<<<(M_ROWS / 256) * (OUT_F / 256), 512, 0, stream>>>(Xb, Wp, bs, out);
}

// Round 13
// 315.551 us; speedup vs baseline: 1.1971x; 1.0700x over previous
//
#include <hip/hip_runtime.h>
#include <hip/hip_bf16.h>
#include <stdint.h>

typedef __bf16 bf16_t;
typedef bf16_t bf16x8 __attribute__((ext_vector_type(8)));
typedef float f32x4 __attribute__((ext_vector_type(4)));

#define IN_F 4096
#define OUT_F 4096
#define M_ROWS 8192
#define RANK 16

// ---------------------------------------------------------------------------
// Kernel 1: dequantize 4-bit -> fp32, fold LoRA (Wp = W + B*A), store bf16.
// Block covers 8 o-rows x 256 i-cols so lora_A is fetched once per block.
// (r8 version verbatim — measured ~36-40us together with the cast kernel.)
// ---------------------------------------------------------------------------
__global__ __launch_bounds__(256)
void dequant_lora_kernel(const int* __restrict__ qw, const float* __restrict__ wmax,
                         const float* __restrict__ lA, const float* __restrict__ lB,
                         bf16_t* __restrict__ Wp) {
  const int bid = blockIdx.x;
  const int bo = bid >> 4;
  const int bi = bid & 15;
  const int t  = threadIdx.x;
  const int o  = bo * 8 + (t >> 5);
  const int i0 = bi * 256 + (t & 31) * 8;
  const int f0 = o * IN_F + i0;

  const int4 q4 = *(const int4*)(qw + (f0 >> 1));
  const float scale = wmax[f0 >> 6];
  const float st = scale * (2.0f / 15.0f);

  float v[8];
  {
    const int q0 = q4.x, q1 = q4.y, q2 = q4.z, q3 = q4.w;
    v[0] = (float)(q0 & 15)        * st - scale;
    v[1] = (float)((q0 >> 4) & 15) * st - scale;
    v[2] = (float)(q1 & 15)        * st - scale;
    v[3] = (float)((q1 >> 4) & 15) * st - scale;
    v[4] = (float)(q2 & 15)        * st - scale;
    v[5] = (float)((q2 >> 4) & 15) * st - scale;
    v[6] = (float)(q3 & 15)        * st - scale;
    v[7] = (float)((q3 >> 4) & 15) * st - scale;
  }

  const float* Brow = lB + o * RANK;
#pragma unroll
  for (int r = 0; r < RANK; ++r) {
    const float br = Brow[r];
    const float4 a0 = *(const float4*)(lA + r * IN_F + i0);
    const float4 a1 = *(const float4*)(lA + r * IN_F + i0 + 4);
    v[0] += br * a0.x; v[1] += br * a0.y; v[2] += br * a0.z; v[3] += br * a0.w;
    v[4] += br * a1.x; v[5] += br * a1.y; v[6] += br * a1.z; v[7] += br * a1.w;
  }

  bf16x8 ov;
#pragma unroll
  for (int j = 0; j < 8; ++j) ov[j] = (bf16_t)v[j];
  *(bf16x8*)(Wp + (size_t)f0) = ov;
}

// ---------------------------------------------------------------------------
// Kernel 2: x fp32 -> bf16 (vectorized, separate launch — faster than merged)
// ---------------------------------------------------------------------------
__global__ __launch_bounds__(256)
void f32_to_bf16_kernel(const float* __restrict__ x, bf16_t* __restrict__ xb) {
  const size_t tid = (size_t)blockIdx.x * 256 + threadIdx.x;
  const float4 a0 = *(const float4*)(x + tid * 8);
  const float4 a1 = *(const float4*)(x + tid * 8 + 4);
  bf16x8 o;
  o[0] = (bf16_t)a0.x; o[1] = (bf16_t)a0.y; o[2] = (bf16_t)a0.z; o[3] = (bf16_t)a0.w;
  o[4] = (bf16_t)a1.x; o[5] = (bf16_t)a1.y; o[6] = (bf16_t)a1.z; o[7] = (bf16_t)a1.w;
  *(bf16x8*)(xb + tid * 8) = o;
}

// ---------------------------------------------------------------------------
// Kernel 3 (r5 verbatim — best measured GEMM: 259-261us, 0 conflicts):
// 256x256 GEMM, 16x16x32 MFMA. Register-pipelined phases (reads for p+1
// issued before p's MFMA; compiler emits counted lgkm waits), ONE boundary
// per tile: barrier -> stage t+2 (8 gloads) -> counted WAIT_VM(8) -> barrier
// -> prefetch next ph0 fragments. Never vmcnt(0) until the final drain.
// B frags double-banked (bFe/bFo).
// ---------------------------------------------------------------------------
__device__ __forceinline__ void gld(const bf16_t* src, char* dst) {
  __builtin_amdgcn_global_load_lds((const __attribute__((address_space(1))) void*)src,
                                   (__attribute__((address_space(3))) void*)dst, 16, 0, 0);
}

#define BARRIER() __builtin_amdgcn_s_barrier()
#define SBAR()    __builtin_amdgcn_sched_barrier(0)
#define WAIT_VM(n) asm volatile("s_waitcnt vmcnt(" #n ")" ::: "memory")

#define LDA(buf, m, cb) (*(const bf16x8*)(ldsA + ((buf)*32768 + aRowB + (m)*2048 + (cb))))
#define LDB(buf, n, cb) (*(const bf16x8*)(ldsB + ((buf)*32768 + bRowB + (n)*2048 + (cb))))

#define STAGE_A4(kt, buf) do { \
  _Pragma("unroll") for (int g = 0; g < 4; ++g) \
    gld(Asrc + ((size_t)g*64*IN_F + (size_t)(kt)*64), ldsA + ((buf)*32768 + g*8192 + tid*16)); \
} while (0)
#define STAGE_B4(kt, buf) do { \
  _Pragma("unroll") for (int g = 0; g < 4; ++g) \
    gld(Bsrc + ((size_t)g*64*IN_F + (size_t)(kt)*64), ldsB + ((buf)*32768 + g*8192 + tid*16)); \
} while (0)

#define LOADA2(dst, m0, buf) do { \
  dst[0][0] = LDA(buf, m0,     cA0); dst[0][1] = LDA(buf, m0,     cA1); \
  dst[1][0] = LDA(buf, (m0)+1, cA0); dst[1][1] = LDA(buf, (m0)+1, cA1); \
} while (0)

#define PREFETCH12(buf, BFN) do { \
  LOADA2(aF0, 0, buf); \
  _Pragma("unroll") for (int n = 0; n < 4; ++n) { \
    BFN[n][0] = LDB(buf, n, cA0); BFN[n][1] = LDB(buf, n, cA1); } \
} while (0)

#define MFMA_Q(Q, AF, BF) do { \
  SBAR(); \
  __builtin_amdgcn_s_setprio(1); \
  _Pragma("unroll") for (int kh = 0; kh < 2; ++kh) \
  _Pragma("unroll") for (int mm = 0; mm < 2; ++mm) \
  _Pragma("unroll") for (int n = 0; n < 4; ++n) \
    acc[2*(Q)+mm][n] = __builtin_amdgcn_mfma_f32_16x16x32_bf16( \
        AF[mm][kh], BF[n][kh], acc[2*(Q)+mm][n], 0, 0, 0); \
  __builtin_amdgcn_s_setprio(0); \
} while (0)

#define TILE_BODY(CUR, BFC) do { \
  LOADA2(aF1, 2, CUR); MFMA_Q(0, aF0, BFC); \
  LOADA2(aF0, 4, CUR); MFMA_Q(1, aF1, BFC); \
  LOADA2(aF1, 6, CUR); MFMA_Q(2, aF0, BFC); \
  MFMA_Q(3, aF1, BFC); \
} while (0)

#define TILE_END(CUR, tv, BFN) do { \
  SBAR(); BARRIER(); \
  if ((tv) < 62) { STAGE_A4((tv) + 2, CUR); STAGE_B4((tv) + 2, CUR); \
                   SBAR(); WAIT_VM(8); } \
  else           { WAIT_VM(0); } \
  SBAR(); BARRIER(); SBAR(); \
  PREFETCH12((CUR) ^ 1, BFN); \
} while (0)

__global__ __launch_bounds__(512, 2)
void gemm_pipe_kernel(const bf16_t* __restrict__ Xb, const bf16_t* __restrict__ Wp,
                      const float* __restrict__ bias, float* __restrict__ C) {
  __shared__ __align__(16) bf16_t As[2 * 16384];   // 64 KiB [2buf][256][64]
  __shared__ __align__(16) bf16_t Bs[2 * 16384];   // 64 KiB
  char* ldsA = (char*)As;
  char* ldsB = (char*)Bs;

  const int tid  = threadIdx.x;
  const int lane = tid & 63;
  const int wave = tid >> 6;
  const int wr = wave >> 2;           // 0..1 -> M half
  const int wc = wave & 3;            // 0..3 -> N quarter
  const int r16 = lane & 15;
  const int kg  = lane >> 4;          // 0..3

  const int bid = blockIdx.x;
  const int bm = bid >> 4;            // 0..31
  const int bn = bid & 15;            // 0..15

  // staging: per-thread row + pre-swizzled source column (both-sides pair)
  const int sr = tid >> 3;                          // 0..63
  const int sc = ((tid & 7) ^ (sr & 7)) << 3;       // element col (swizzled)
  const bf16_t* Asrc = Xb + (size_t)(bm * 256 + sr) * IN_F + sc;
  const bf16_t* Bsrc = Wp + (size_t)(bn * 256 + sr) * IN_F + sc;

  // read-side offsets (proven conflict-free addressing family)
  const int aRowB = (wr * 128 + r16) * 128;         // byte row offset in A tile
  const int bRowB = (wc * 64 + r16) * 128;          // byte row offset in B tile
  const int cA0 = (kg * 16) ^ ((r16 & 7) << 4);     // swizzled col byte, k-half 0
  const int cA1 = cA0 ^ 64;                         // k-half 1

  f32x4 acc[8][4] = {};
  bf16x8 aF0[2][2], aF1[2][2], bFe[4][2], bFo[4][2];

  // prologue: stage tiles 0 and 1; prefetch tile-0 ph0 fragments
  STAGE_A4(0, 0); STAGE_B4(0, 0);
  STAGE_A4(1, 1); STAGE_B4(1, 1);
  WAIT_VM(8);                 // tile 0 landed (tile 1's 8 still in flight)
  BARRIER(); SBAR();
  PREFETCH12(0, bFe);

  for (int tt = 0; tt < 62; tt += 2) {
    TILE_BODY(0, bFe); TILE_END(0, tt,     bFo);
    TILE_BODY(1, bFo); TILE_END(1, tt + 1, bFe);
  }
  TILE_BODY(0, bFe); TILE_END(0, 62, bFo);   // t=62 (drains to 0, prefetches t63)
  TILE_BODY(1, bFo);                         // t=63

  // epilogue: C/D layout col=lane&15, row=kg*4+reg (m89-verified)
#pragma unroll
  for (int n = 0; n < 4; ++n) {
    const int col = bn * 256 + wc * 64 + n * 16 + r16;
    const float bv = bias[col];
#pragma unroll
    for (int m = 0; m < 8; ++m) {
      const int row0 = bm * 256 + wr * 128 + m * 16 + kg * 4;
#pragma unroll
      for (int r = 0; r < 4; ++r)
        C[(size_t)(row0 + r) * OUT_F + col] = acc[m][n][r] + bv;
    }
  }
}

// ---------------------------------------------------------------------------
extern "C" void kernel_launch(void* const* d_in, const int* in_sizes, int n_in,
                              void* d_out, int out_size, void* d_ws, size_t ws_size,
                              hipStream_t stream) {
  const float* x  = (const float*)d_in[0];
  const int*   qw = (const int*)d_in[1];
  const float* wm = (const float*)d_in[2];
  const float* lA = (const float*)d_in[3];
  const float* lB = (const float*)d_in[4];
  const float* bs = (const float*)d_in[5];
  float* out = (float*)d_out;

  bf16_t* Wp = (bf16_t*)d_ws;                                        // 33.5 MB
  bf16_t* Xb = (bf16_t*)((char*)d_ws + (size_t)OUT_F * IN_F * 2);    // 67 MB

  dequant_lora_kernel<<<8192, 256, 0, stream>>>(qw, wm, lA, lB, Wp);
  f32_to_bf16_kernel<<<M_ROWS * IN_F / 8 / 256, 256, 0, stream>>>(x, Xb);
  gemm_pipe_kernel<<<(M_ROWS / 256) * (OUT_F / 256), 512, 0, stream>>>(Xb, Wp, bs, out);
}